// Round 1
// baseline (625.837 us; speedup 1.0000x reference)
//
#include <hip/hip_runtime.h>
#include <math.h>

// qkv: (B=4, S=4096, 3, H=16, D=128) fp32. RoPE on t=0 (q) and t=1 (k),
// pairing d with d+64, angle = (offset[b]+s) * 10000^(-d/64), d in [0,64).
// t=2 (v) is a straight copy. Output layout == input layout.

#define B_NUM 4
#define S_LEN 4096
#define H_NUM 16
#define D_DIM 128
#define HALF  64

// -log2(10000)/64
#define NEG_L2B_OVER_HALF (-0.2076205059304601f)

__global__ __launch_bounds__(256) void rope_kernel(
    const float4* __restrict__ in,
    const int* __restrict__ offsets,
    float4* __restrict__ out)
{
    const int bx  = blockIdx.x;          // bx = ((b*S + s)*3 + t)
    const int t   = bx % 3;
    const int bs  = bx / 3;              // b*S + s
    const int s   = bs & (S_LEN - 1);
    const int b   = bs >> 12;

    const int tid = threadIdx.x;
    const int c4  = tid & 15;            // float4 index within first half [0,16)
    const int h   = tid >> 4;            // head [0,16)

    // flat float4 index: ((bx*H + h) * D + 4*c4) / 4
    const long base = ((long)bx * H_NUM + h) * (D_DIM / 4) + c4;

    float4 x1 = in[base];                // dims [4*c4, 4*c4+4)
    float4 x2 = in[base + HALF / 4];     // dims [64+4*c4, 64+4*c4+4)

    if (t < 2) {
        const float pos = (float)(offsets[b] + s);
        const float j0  = (float)(c4 * 4);

        float4 o1, o2;
        float* p1 = &o1.x; float* p2 = &o2.x;
        const float* q1 = &x1.x; const float* q2 = &x2.x;
        #pragma unroll
        for (int k = 0; k < 4; ++k) {
            float j    = j0 + (float)k;
            float invf = exp2f(j * NEG_L2B_OVER_HALF);
            float f    = pos * invf;
            float sv, cv;
            sincosf(f, &sv, &cv);
            p1[k] = q1[k] * cv - q2[k] * sv;
            p2[k] = q1[k] * sv + q2[k] * cv;
        }
        x1 = o1;
        x2 = o2;
    }
    // t == 2: passthrough (v)

    out[base]            = x1;
    out[base + HALF / 4] = x2;
}

extern "C" void kernel_launch(void* const* d_in, const int* in_sizes, int n_in,
                              void* d_out, int out_size, void* d_ws, size_t ws_size,
                              hipStream_t stream)
{
    const float4* qkv = (const float4*)d_in[0];
    const int* offsets = (const int*)d_in[1];
    float4* outp = (float4*)d_out;

    const int grid = B_NUM * S_LEN * 3;   // 49152 blocks, one per (b,s,t)
    rope_kernel<<<grid, 256, 0, stream>>>(qkv, offsets, outp);
}